// Round 1
// baseline (355.165 us; speedup 1.0000x reference)
//
#include <hip/hip_runtime.h>
#include <hip/hip_bf16.h>

#define DM 2048
#define NH 4
#define DI 64
#define TQS 4096
#define TKS 4096
#define BB 2

typedef __attribute__((ext_vector_type(4))) float f32x4;
typedef __attribute__((ext_vector_type(8))) short bf16x8;

__device__ __forceinline__ short f2bf(float f) {
  __hip_bfloat16 h = __float2bfloat16(f);
  return __builtin_bit_cast(short, h);
}

__device__ __forceinline__ bf16x8 cvt8(f32x4 a, f32x4 b) {
  bf16x8 r;
  r[0] = f2bf(a[0]); r[1] = f2bf(a[1]); r[2] = f2bf(a[2]); r[3] = f2bf(a[3]);
  r[4] = f2bf(b[0]); r[5] = f2bf(b[1]); r[6] = f2bf(b[2]); r[7] = f2bf(b[3]);
  return r;
}

// WqwT[320][2048]: rows 0-255 = Wq cols, 256-259 = Ww cols, 260-319 = 0.
__global__ __launch_bounds__(256) void transpose_qw(const float* __restrict__ Wq,
                                                    const float* __restrict__ Ww,
                                                    short* __restrict__ WT) {
  int idx = blockIdx.x * 256 + threadIdx.x;  // n*2048 + k
  int n = idx >> 11, k = idx & 2047;
  float v = 0.f;
  if (n < 256) v = Wq[(size_t)k * 256 + n];
  else if (n < 260) v = Ww[(size_t)k * 4 + (n - 256)];
  WT[idx] = f2bf(v);
}

// WkT[64][2048]
__global__ __launch_bounds__(256) void transpose_k(const float* __restrict__ Wk,
                                                   short* __restrict__ WT) {
  int idx = blockIdx.x * 256 + threadIdx.x;
  int n = idx >> 11, k = idx & 2047;
  WT[idx] = f2bf(Wk[(size_t)k * 64 + n]);
}

// One block = 32 rows x (NJ*4 waves' worth of) columns. Waves split COLUMNS:
// wave w owns column-tiles {w, 4+w, 8+w, 12+w} (+ {16+w} for q-path); all waves
// read the same 32 A rows (L1-shared).
// BOTH streams (A raw f32 from x, B bf16 weights) are pipelined 4 stages deep
// in registers, issued in consistent A-then-B order each iteration, so the
// single ordered vmcnt queue retains ~3.5 iterations of loads in flight ahead
// of every MFMA cluster. (Previous version: B was 1-deep and issued after A
// refills -> every MFMA wait force-drained A loads issued 1 iter earlier ->
// effective pipeline depth ~1 iter regardless of A depth.)
template <int NJ, bool QP>
__device__ __forceinline__ void proj_body(const float* __restrict__ X,
                                          const short* __restrict__ WT,
                                          short* __restrict__ O,
                                          float* __restrict__ wI, int blk) {
  const int tid = threadIdx.x;
  const int wave = tid >> 6, lane = tid & 63;
  const int l15 = lane & 15, quad = lane >> 4;
  const int m0 = blk * 32;
  const int ldo = QP ? 256 : 64;

  int jt[NJ];
#pragma unroll
  for (int jj = 0; jj < NJ; ++jj) jt[jj] = QP ? (jj < 4 ? jj * 4 + wave : 16 + wave) : wave;

  const float* xbase = X + (size_t)(m0 + l15) * DM + quad * 8;
  const short* wb[NJ];
#pragma unroll
  for (int jj = 0; jj < NJ; ++jj) wb[jj] = WT + (size_t)(jt[jj] * 16 + l15) * DM + quad * 8;

  const f32x4 z = {0.f, 0.f, 0.f, 0.f};
  f32x4 acc[NJ][2];
#pragma unroll
  for (int jj = 0; jj < NJ; ++jj)
#pragma unroll
    for (int i = 0; i < 2; ++i) acc[jj][i] = z;

  // 4-deep software pipeline on BOTH streams.
  f32x4 araw[4][2][2];
  bf16x8 bb[4][NJ];
#pragma unroll
  for (int s = 0; s < 4; ++s) {
#pragma unroll
    for (int i = 0; i < 2; ++i) {
      araw[s][i][0] = *(const f32x4*)(xbase + s * 32 + i * 16 * DM);
      araw[s][i][1] = *(const f32x4*)(xbase + s * 32 + i * 16 * DM + 4);
    }
#pragma unroll
    for (int jj = 0; jj < NJ; ++jj) bb[s][jj] = *(const bf16x8*)(wb[jj] + s * 32);
  }

#pragma unroll 4
  for (int ks = 0; ks < 64; ++ks) {
    const int s = ks & 3;  // static under unroll-4 (no scratch, rule #20)
    bf16x8 abf[2];
#pragma unroll
    for (int i = 0; i < 2; ++i) abf[i] = cvt8(araw[s][i][0], araw[s][i][1]);
    // Refill stage s for iter ks+4: A first...
    if (ks < 60) {
      const float* xp = xbase + (ks + 4) * 32;
#pragma unroll
      for (int i = 0; i < 2; ++i) {
        araw[s][i][0] = *(const f32x4*)(xp + i * 16 * DM);
        araw[s][i][1] = *(const f32x4*)(xp + i * 16 * DM + 4);
      }
    }
#pragma unroll
    for (int jj = 0; jj < NJ; ++jj)
#pragma unroll
      for (int i = 0; i < 2; ++i)
        acc[jj][i] = __builtin_amdgcn_mfma_f32_16x16x32_bf16(abf[i], bb[s][jj],
                                                             acc[jj][i], 0, 0, 0);
    // ...then B (after MFMA consumed bb[s]; same relative order every iter).
    if (ks < 60) {
#pragma unroll
      for (int jj = 0; jj < NJ; ++jj)
        bb[s][jj] = *(const bf16x8*)(wb[jj] + (ks + 4) * 32);
    }
  }

  // C/D: row = quad*4 + r, col = l15
#pragma unroll
  for (int jj = 0; jj < NJ; ++jj) {
    if (QP && jt[jj] >= 16) {
      if (jt[jj] == 16 && l15 < 4) {  // Ww columns -> wI (f32)
#pragma unroll
        for (int i = 0; i < 2; ++i)
#pragma unroll
          for (int r = 0; r < 4; ++r)
            wI[(size_t)(m0 + i * 16 + quad * 4 + r) * NH + l15] = acc[jj][i][r];
      }
    } else {
#pragma unroll
      for (int i = 0; i < 2; ++i)
#pragma unroll
        for (int r = 0; r < 4; ++r)
          O[(size_t)(m0 + i * 16 + quad * 4 + r) * ldo + jt[jj] * 16 + l15] =
              f2bf(acc[jj][i][r]);
    }
  }
}

__global__ __launch_bounds__(256, 2) void proj_fused(const float* __restrict__ xq,
                                                     const float* __restrict__ xk,
                                                     const short* __restrict__ WqwT,
                                                     const short* __restrict__ WkT,
                                                     short* __restrict__ qb,
                                                     short* __restrict__ kb,
                                                     float* __restrict__ wIb) {
  if (blockIdx.x < 256)
    proj_body<5, true>(xq, WqwT, qb, wIb, blockIdx.x);
  else
    proj_body<1, false>(xk, WkT, kb, nullptr, blockIdx.x - 256);
}

// out[b][q][k] = sum_h wI[b,q,h] * relu(qb[b,q,h,:] . kb[b,k,:])
// 128x128 tile/block, 4 waves of 64x64. No LDS/barriers; af double-buffered over heads.
__global__ __launch_bounds__(256, 2) void score_kernel(const short* __restrict__ qb,
                                                       const short* __restrict__ kb,
                                                       const float* __restrict__ wI,
                                                       float* __restrict__ out) {
  const int b = blockIdx.z;
  const int qt = blockIdx.y;
  const int kt = blockIdx.x;
  const int tid = threadIdx.x;
  const int wave = tid >> 6, lane = tid & 63;
  const int wm = wave >> 1, wn = wave & 1;
  const int l15 = lane & 15, quad = lane >> 4;

  // Key fragments: B[k=quad*8+j][n=l15]; reused across all heads.
  bf16x8 bf[4][2];
  {
    const short* kbase =
        kb + (size_t)(b * TKS + kt * 128 + wn * 64 + l15) * DI + quad * 8;
#pragma unroll
    for (int j = 0; j < 4; ++j)
#pragma unroll
      for (int ks = 0; ks < 2; ++ks)
        bf[j][ks] = *(const bf16x8*)(kbase + j * 16 * DI + ks * 32);
  }

  const f32x4 z = {0.f, 0.f, 0.f, 0.f};
  f32x4 facc[4][4];
#pragma unroll
  for (int i = 0; i < 4; ++i)
#pragma unroll
    for (int j = 0; j < 4; ++j) facc[i][j] = z;

  const short* qbase =
      qb + (size_t)(b * TQS + qt * 128 + wm * 64 + l15) * (NH * DI) + quad * 8;
  const float* wbase = wI + (size_t)(b * TQS + qt * 128 + wm * 64 + quad * 4) * NH;

  bf16x8 af[2][4][2];
#pragma unroll
  for (int i = 0; i < 4; ++i)
#pragma unroll
    for (int ks = 0; ks < 2; ++ks)
      af[0][i][ks] = *(const bf16x8*)(qbase + i * 16 * (NH * DI) + ks * 32);

#pragma unroll
  for (int h = 0; h < NH; ++h) {
    if (h < NH - 1) {  // prefetch next head's A fragments (covered by MFMA+epilogue)
#pragma unroll
      for (int i = 0; i < 4; ++i)
#pragma unroll
        for (int ks = 0; ks < 2; ++ks)
          af[(h + 1) & 1][i][ks] =
              *(const bf16x8*)(qbase + (h + 1) * DI + i * 16 * (NH * DI) + ks * 32);
    }

    f32x4 acc[4][4];
#pragma unroll
    for (int i = 0; i < 4; ++i)
#pragma unroll
      for (int j = 0; j < 4; ++j) acc[i][j] = z;

#pragma unroll
    for (int ks = 0; ks < 2; ++ks)
#pragma unroll
      for (int i = 0; i < 4; ++i)
#pragma unroll
        for (int j = 0; j < 4; ++j)
          acc[i][j] = __builtin_amdgcn_mfma_f32_16x16x32_bf16(
              af[h & 1][i][ks], bf[j][ks], acc[i][j], 0, 0, 0);

#pragma unroll
    for (int i = 0; i < 4; ++i) {
      float wv[4];
#pragma unroll
      for (int r = 0; r < 4; ++r) wv[r] = wbase[(i * 16 + r) * NH + h];
#pragma unroll
      for (int j = 0; j < 4; ++j)
#pragma unroll
        for (int r = 0; r < 4; ++r)
          facc[i][j][r] += wv[r] * fmaxf(acc[i][j][r], 0.f);
    }
  }

  float* obase = out + (size_t)b * TQS * TKS +
                 (size_t)(qt * 128 + wm * 64 + quad * 4) * TKS + kt * 128 + wn * 64 + l15;
#pragma unroll
  for (int i = 0; i < 4; ++i)
#pragma unroll
    for (int r = 0; r < 4; ++r)
#pragma unroll
      for (int j = 0; j < 4; ++j)
        __builtin_nontemporal_store(facc[i][j][r],
                                    &obase[(size_t)(i * 16 + r) * TKS + j * 16]);
}

extern "C" void kernel_launch(void* const* d_in, const int* in_sizes, int n_in,
                              void* d_out, int out_size, void* d_ws, size_t ws_size,
                              hipStream_t stream) {
  const float* x_q = (const float*)d_in[0];  // [2,4096,2048]
  const float* x_k = (const float*)d_in[1];  // [2,4096,2048]
  const float* Wq  = (const float*)d_in[2];  // [2048,256]
  const float* Ww  = (const float*)d_in[3];  // [2048,4]
  const float* Wk  = (const float*)d_in[4];  // [2048,64]
  float* out = (float*)d_out;                // [2,4096,4096]

  char* ws = (char*)d_ws;
  short* qbuf = (short*)(ws);                              // 8192*256 bf16 = 4 MB
  short* kbuf = (short*)(ws + (4u << 20));                 // 8192*64  bf16 = 1 MB
  float* wIb  = (float*)(ws + (5u << 20));                 // 8192*4 f32 = 128 KB
  short* WqwT = (short*)(ws + (5u << 20) + (128u << 10));  // 320*2048 bf16 = 1.25 MB
  short* WkT  = (short*)(ws + (7u << 20));                 // 64*2048 bf16 = 256 KB

  transpose_qw<<<(320 * 2048) / 256, 256, 0, stream>>>(Wq, Ww, WqwT);
  transpose_k<<<(64 * 2048) / 256, 256, 0, stream>>>(Wk, WkT);

  // Fused projections: blocks 0-255 -> q (+w), 256-511 -> k. x read exactly once.
  proj_fused<<<512, 256, 0, stream>>>(x_q, x_k, WqwT, WkT, qbuf, kbuf, wIb);

  score_kernel<<<dim3(TKS / 128, TQS / 128, BB), 256, 0, stream>>>(qbuf, kbuf, wIb, out);
}

// Round 2
// 301.584 us; speedup vs baseline: 1.1777x; 1.1777x over previous
//
#include <hip/hip_runtime.h>
#include <hip/hip_bf16.h>

#define DM 2048
#define NH 4
#define DI 64
#define TQS 4096
#define TKS 4096
#define BB 2

typedef __attribute__((ext_vector_type(4))) float f32x4;
typedef __attribute__((ext_vector_type(8))) short bf16x8;

typedef __attribute__((address_space(1))) const void gvoid;
typedef __attribute__((address_space(3))) void lvoid;

__device__ __forceinline__ short f2bf(float f) {
  __hip_bfloat16 h = __float2bfloat16(f);
  return __builtin_bit_cast(short, h);
}

__device__ __forceinline__ bf16x8 cvt8(f32x4 a, f32x4 b) {
  bf16x8 r;
  r[0] = f2bf(a[0]); r[1] = f2bf(a[1]); r[2] = f2bf(a[2]); r[3] = f2bf(a[3]);
  r[4] = f2bf(b[0]); r[5] = f2bf(b[1]); r[6] = f2bf(b[2]); r[7] = f2bf(b[3]);
  return r;
}

// WqwT[320][2048]: rows 0-255 = Wq cols, 256-259 = Ww cols, 260-319 = 0.
__global__ __launch_bounds__(256) void transpose_qw(const float* __restrict__ Wq,
                                                    const float* __restrict__ Ww,
                                                    short* __restrict__ WT) {
  int idx = blockIdx.x * 256 + threadIdx.x;  // n*2048 + k
  int n = idx >> 11, k = idx & 2047;
  float v = 0.f;
  if (n < 256) v = Wq[(size_t)k * 256 + n];
  else if (n < 260) v = Ww[(size_t)k * 4 + (n - 256)];
  WT[idx] = f2bf(v);
}

// WkT[64][2048]
__global__ __launch_bounds__(256) void transpose_k(const float* __restrict__ Wk,
                                                   short* __restrict__ WT) {
  int idx = blockIdx.x * 256 + threadIdx.x;
  int n = idx >> 11, k = idx & 2047;
  WT[idx] = f2bf(Wk[(size_t)k * 64 + n]);
}

// proj v3: 2-phase LDS-staged (m97 structure). Round-1 lesson: register-resident
// prefetch from global collapses (VGPR=116 < pipeline's 184 -> compiler sank the
// loads, depth ~1, 4650 cyc/k-step all stall). global_load_lds + barrier pacing
// cannot be collapsed by the scheduler.
// Block = 32 rows x all columns; 4 waves split columns (NJ tiles each).
// A-tile: [32 rows][64 f32] staged per BK=64, double-buffered (16 KB LDS).
// Swizzle (rule #21, both-sides-or-neither): LDS dest linear by tid; global
// SOURCE pre-swizzled chunk c_l -> c_l ^ (row&15); ds_read applies same XOR.
// Each 16-lane read phase then spans all 16 chunks -> conflict-free b128.
template <int NJ, bool QP>
__device__ __forceinline__ void proj_body(const float* __restrict__ X,
                                          const short* __restrict__ WT,
                                          short* __restrict__ O,
                                          float* __restrict__ wI, int blk,
                                          float* As /* [2][2048] LDS */) {
  const int tid = threadIdx.x;
  const int wave = tid >> 6, lane = tid & 63;
  const int l15 = lane & 15, quad = lane >> 4;
  const int m0 = blk * 32;
  const int ldo = QP ? 256 : 64;

  int jt[NJ];
#pragma unroll
  for (int jj = 0; jj < NJ; ++jj) jt[jj] = QP ? (jj < 4 ? jj * 4 + wave : 16 + wave) : wave;

  const short* wb[NJ];
#pragma unroll
  for (int jj = 0; jj < NJ; ++jj) wb[jj] = WT + (size_t)(jt[jj] * 16 + l15) * DM + quad * 8;

  // Stage source: thread t fills LDS linear slots {t*16, 4096 + t*16} (rows
  // srow and srow+16). Source chunk pre-swizzled: (t&15) ^ srow.
  const int srow = tid >> 4;                 // 0..15; == (row & 15) for both insts
  const int schunk = (tid & 15) ^ srow;      // inverse-swizzled 16B chunk
  const float* s0 = X + (size_t)(m0 + srow) * DM + schunk * 4;
  const float* s1 = X + (size_t)(m0 + 16 + srow) * DM + schunk * 4;
  const int d0 = tid * 16;
  const int d1 = 4096 + tid * 16;

  const f32x4 z = {0.f, 0.f, 0.f, 0.f};
  f32x4 acc[NJ][2];
#pragma unroll
  for (int jj = 0; jj < NJ; ++jj)
#pragma unroll
    for (int i = 0; i < 2; ++i) acc[jj][i] = z;

  char* lbase = (char*)As;

  // prologue: stage t=0 into buf0
  __builtin_amdgcn_global_load_lds((gvoid*)s0, (lvoid*)(lbase + d0), 16, 0, 0);
  __builtin_amdgcn_global_load_lds((gvoid*)s1, (lvoid*)(lbase + d1), 16, 0, 0);
  __syncthreads();

  int cur = 0;
#pragma unroll 2
  for (int t = 0; t < 32; ++t) {
    // B for stage t FIRST (register loads, L2-hit): their vmcnt wait before the
    // MFMA cluster then leaves the stage-(t+1) lds-loads in flight.
    bf16x8 bbv[NJ][2];
#pragma unroll
    for (int jj = 0; jj < NJ; ++jj)
#pragma unroll
      for (int ks = 0; ks < 2; ++ks)
        bbv[jj][ks] = *(const bf16x8*)(wb[jj] + t * 64 + ks * 32);
    __builtin_amdgcn_sched_barrier(0);  // pin: B issued before stage loads

    if (t < 31) {  // issue next stage into the other buffer
      const float* g0 = s0 + (t + 1) * 64;
      const float* g1 = s1 + (t + 1) * 64;
      char* l = lbase + (cur ^ 1) * 8192;
      __builtin_amdgcn_global_load_lds((gvoid*)g0, (lvoid*)(l + d0), 16, 0, 0);
      __builtin_amdgcn_global_load_lds((gvoid*)g1, (lvoid*)(l + d1), 16, 0, 0);
    }
    __builtin_amdgcn_sched_barrier(0);  // pin: stage issued before compute

    // A fragments from LDS buf[cur]: lane (l15,quad), row r=i*16+l15,
    // k = ks*32 + quad*8 (8 consecutive f32 = chunks cg, cg+1; XOR l15).
    const float* Ab = As + cur * 2048;
    bf16x8 abf[2][2];
#pragma unroll
    for (int i = 0; i < 2; ++i)
#pragma unroll
      for (int ks = 0; ks < 2; ++ks) {
        const int rb = (i * 16 + l15) * 64;
        const int cg = ks * 8 + quad * 2;
        f32x4 a0 = *(const f32x4*)(Ab + rb + ((cg ^ l15) << 2));
        f32x4 a1 = *(const f32x4*)(Ab + rb + (((cg + 1) ^ l15) << 2));
        abf[i][ks] = cvt8(a0, a1);
      }

#pragma unroll
    for (int jj = 0; jj < NJ; ++jj)
#pragma unroll
      for (int i = 0; i < 2; ++i)
#pragma unroll
        for (int ks = 0; ks < 2; ++ks)
          acc[jj][i] = __builtin_amdgcn_mfma_f32_16x16x32_bf16(abf[i][ks], bbv[jj][ks],
                                                               acc[jj][i], 0, 0, 0);

    __syncthreads();  // drains vmcnt -> buf[cur^1] complete; LDS reuse safe
    cur ^= 1;
  }

  // C/D: row = quad*4 + r, col = l15
#pragma unroll
  for (int jj = 0; jj < NJ; ++jj) {
    if (QP && jt[jj] >= 16) {
      if (jt[jj] == 16 && l15 < 4) {  // Ww columns -> wI (f32)
#pragma unroll
        for (int i = 0; i < 2; ++i)
#pragma unroll
          for (int r = 0; r < 4; ++r)
            wI[(size_t)(m0 + i * 16 + quad * 4 + r) * NH + l15] = acc[jj][i][r];
      }
    } else {
#pragma unroll
      for (int i = 0; i < 2; ++i)
#pragma unroll
        for (int r = 0; r < 4; ++r)
          O[(size_t)(m0 + i * 16 + quad * 4 + r) * ldo + jt[jj] * 16 + l15] =
              f2bf(acc[jj][i][r]);
    }
  }
}

__global__ __launch_bounds__(256, 2) void proj_fused(const float* __restrict__ xq,
                                                     const float* __restrict__ xk,
                                                     const short* __restrict__ WqwT,
                                                     const short* __restrict__ WkT,
                                                     short* __restrict__ qb,
                                                     short* __restrict__ kb,
                                                     float* __restrict__ wIb) {
  __shared__ __align__(16) float As[2][2048];  // 16 KB: 2 x [32 rows][64 f32]
  if (blockIdx.x < 256)
    proj_body<5, true>(xq, WqwT, qb, wIb, blockIdx.x, &As[0][0]);
  else
    proj_body<1, false>(xk, WkT, kb, nullptr, blockIdx.x - 256, &As[0][0]);
}

// out[b][q][k] = sum_h wI[b,q,h] * relu(qb[b,q,h,:] . kb[b,k,:])
// 128x128 tile/block, 4 waves of 64x64. No LDS/barriers; af double-buffered over heads.
__global__ __launch_bounds__(256, 2) void score_kernel(const short* __restrict__ qb,
                                                       const short* __restrict__ kb,
                                                       const float* __restrict__ wI,
                                                       float* __restrict__ out) {
  const int b = blockIdx.z;
  const int qt = blockIdx.y;
  const int kt = blockIdx.x;
  const int tid = threadIdx.x;
  const int wave = tid >> 6, lane = tid & 63;
  const int wm = wave >> 1, wn = wave & 1;
  const int l15 = lane & 15, quad = lane >> 4;

  // Key fragments: B[k=quad*8+j][n=l15]; reused across all heads.
  bf16x8 bf[4][2];
  {
    const short* kbase =
        kb + (size_t)(b * TKS + kt * 128 + wn * 64 + l15) * DI + quad * 8;
#pragma unroll
    for (int j = 0; j < 4; ++j)
#pragma unroll
      for (int ks = 0; ks < 2; ++ks)
        bf[j][ks] = *(const bf16x8*)(kbase + j * 16 * DI + ks * 32);
  }

  const f32x4 z = {0.f, 0.f, 0.f, 0.f};
  f32x4 facc[4][4];
#pragma unroll
  for (int i = 0; i < 4; ++i)
#pragma unroll
    for (int j = 0; j < 4; ++j) facc[i][j] = z;

  const short* qbase =
      qb + (size_t)(b * TQS + qt * 128 + wm * 64 + l15) * (NH * DI) + quad * 8;
  const float* wbase = wI + (size_t)(b * TQS + qt * 128 + wm * 64 + quad * 4) * NH;

  bf16x8 af[2][4][2];
#pragma unroll
  for (int i = 0; i < 4; ++i)
#pragma unroll
    for (int ks = 0; ks < 2; ++ks)
      af[0][i][ks] = *(const bf16x8*)(qbase + i * 16 * (NH * DI) + ks * 32);

#pragma unroll
  for (int h = 0; h < NH; ++h) {
    if (h < NH - 1) {  // prefetch next head's A fragments (covered by MFMA+epilogue)
#pragma unroll
      for (int i = 0; i < 4; ++i)
#pragma unroll
        for (int ks = 0; ks < 2; ++ks)
          af[(h + 1) & 1][i][ks] =
              *(const bf16x8*)(qbase + (h + 1) * DI + i * 16 * (NH * DI) + ks * 32);
    }

    f32x4 acc[4][4];
#pragma unroll
    for (int i = 0; i < 4; ++i)
#pragma unroll
      for (int j = 0; j < 4; ++j) acc[i][j] = z;

#pragma unroll
    for (int ks = 0; ks < 2; ++ks)
#pragma unroll
      for (int i = 0; i < 4; ++i)
#pragma unroll
        for (int j = 0; j < 4; ++j)
          acc[i][j] = __builtin_amdgcn_mfma_f32_16x16x32_bf16(
              af[h & 1][i][ks], bf[j][ks], acc[i][j], 0, 0, 0);

#pragma unroll
    for (int i = 0; i < 4; ++i) {
      float wv[4];
#pragma unroll
      for (int r = 0; r < 4; ++r) wv[r] = wbase[(i * 16 + r) * NH + h];
#pragma unroll
      for (int j = 0; j < 4; ++j)
#pragma unroll
        for (int r = 0; r < 4; ++r)
          facc[i][j][r] += wv[r] * fmaxf(acc[i][j][r], 0.f);
    }
  }

  float* obase = out + (size_t)b * TQS * TKS +
                 (size_t)(qt * 128 + wm * 64 + quad * 4) * TKS + kt * 128 + wn * 64 + l15;
#pragma unroll
  for (int i = 0; i < 4; ++i)
#pragma unroll
    for (int r = 0; r < 4; ++r)
#pragma unroll
      for (int j = 0; j < 4; ++j)
        __builtin_nontemporal_store(facc[i][j][r],
                                    &obase[(size_t)(i * 16 + r) * TKS + j * 16]);
}

extern "C" void kernel_launch(void* const* d_in, const int* in_sizes, int n_in,
                              void* d_out, int out_size, void* d_ws, size_t ws_size,
                              hipStream_t stream) {
  const float* x_q = (const float*)d_in[0];  // [2,4096,2048]
  const float* x_k = (const float*)d_in[1];  // [2,4096,2048]
  const float* Wq  = (const float*)d_in[2];  // [2048,256]
  const float* Ww  = (const float*)d_in[3];  // [2048,4]
  const float* Wk  = (const float*)d_in[4];  // [2048,64]
  float* out = (float*)d_out;                // [2,4096,4096]

  char* ws = (char*)d_ws;
  short* qbuf = (short*)(ws);                              // 8192*256 bf16 = 4 MB
  short* kbuf = (short*)(ws + (4u << 20));                 // 8192*64  bf16 = 1 MB
  float* wIb  = (float*)(ws + (5u << 20));                 // 8192*4 f32 = 128 KB
  short* WqwT = (short*)(ws + (5u << 20) + (128u << 10));  // 320*2048 bf16 = 1.25 MB
  short* WkT  = (short*)(ws + (7u << 20));                 // 64*2048 bf16 = 256 KB

  transpose_qw<<<(320 * 2048) / 256, 256, 0, stream>>>(Wq, Ww, WqwT);
  transpose_k<<<(64 * 2048) / 256, 256, 0, stream>>>(Wk, WkT);

  // Fused projections: blocks 0-255 -> q (+w), 256-511 -> k. x read exactly once.
  proj_fused<<<512, 256, 0, stream>>>(x_q, x_k, WqwT, WkT, qbuf, kbuf, wIb);

  score_kernel<<<dim3(TKS / 128, TQS / 128, BB), 256, 0, stream>>>(qbuf, kbuf, wIb, out);
}